// Round 6
// baseline (699.962 us; speedup 1.0000x reference)
//
#include <hip/hip_runtime.h>

#define EPSB 1e-5f
#define NEG 0.2f

__device__ __forceinline__ float lrelu(float y) { return y >= 0.f ? y : NEG * y; }

// async global->LDS 16B/lane (wave-uniform LDS dest, per-lane global src)
typedef const __attribute__((address_space(1))) unsigned int gas1_u32;
typedef __attribute__((address_space(3))) unsigned int as3_u32;
__device__ __forceinline__ void gload16(const float* g, float* l) {
  __builtin_amdgcn_global_load_lds((gas1_u32*)g, (as3_u32*)l, 16, 0, 0);
}
#define WAITVM(N) asm volatile("s_waitcnt vmcnt(" #N ")" ::: "memory")
#define WAITLGKM0 asm volatile("s_waitcnt lgkmcnt(0)" ::: "memory")

// ---------------------------------------------------------------------------
// Fused conv frontend (unchanged, validated): output xt[p][b][s].
// ---------------------------------------------------------------------------
__global__ __launch_bounds__(256) void k_front(
    const float* __restrict__ data, const float* __restrict__ w1,
    const float* __restrict__ w2, const float* __restrict__ w3,
    const float* __restrict__ lw, const float* __restrict__ bg,
    const float* __restrict__ bb, const float* __restrict__ bm,
    const float* __restrict__ bv, float* __restrict__ xt)
{
  __shared__ float x1s[32][132];
  __shared__ float x2s[32][40];
  __shared__ float x3s[32][20];
  const int b = blockIdx.x >> 3, q = blockIdx.x & 7, t = threadIdx.x;
  const int o1s = (937*q)/8, o1e = (937*(q+1))/8;
  const int o2s = (234*q)/8, o2e = (234*(q+1))/8;
  const int o3s = (116*q)/8, o3e = (116*(q+1))/8;
  int n2s = min(o2s, 2*o3s);
  int n2e = max(o2e, 2*(o3e-1)+4); if (n2e > 234) n2e = 234;
  int n1s = min(o1s, 4*n2s);
  int n1e = max(o1e, 4*(n2e-1)+5); if (n1e > 937) n1e = 937;
  const int w1w = n1e - n1s, w2w = n2e - n2s, w3w = o3e - o3s;

  for (int idx = t; idx < 32*w1w; idx += 256) {
    int c = idx / w1w, j = n1s + idx % w1w;
    float acc = 0.f;
    int base = 5*j - 2;
    #pragma unroll
    for (int k = 0; k < 5; ++k) {
      int pos = base + k;
      float d = (pos >= 0 && pos < 4681) ? data[b*4681 + pos] : 0.f;
      acc += w1[c*5 + k] * d;
    }
    float sc = bg[c] * rsqrtf(bv[c] + EPSB);
    x1s[c][j - n1s] = lrelu((acc - bm[c]) * sc + bb[c]);
  }
  __syncthreads();
  for (int idx = t; idx < 32*w2w; idx += 256) {
    int c = idx / w2w, j = n2s + idx % w2w;
    float acc = 0.f;
    int col = 4*j - n1s;
    for (int ci = 0; ci < 32; ++ci) {
      #pragma unroll
      for (int k = 0; k < 5; ++k) acc += w2[(c*32 + ci)*5 + k] * x1s[ci][col + k];
    }
    float sc = bg[32+c] * rsqrtf(bv[32+c] + EPSB);
    x2s[c][j - n2s] = lrelu((acc - bm[32+c]) * sc + bb[32+c]);
  }
  __syncthreads();
  for (int idx = t; idx < 32*w3w; idx += 256) {
    int c = idx / w3w, j = o3s + idx % w3w;
    float acc = 0.f;
    int col = 2*j - n2s;
    for (int ci = 0; ci < 32; ++ci) {
      #pragma unroll
      for (int k = 0; k < 4; ++k) acc += w3[(c*32 + ci)*4 + k] * x2s[ci][col + k];
    }
    float sc = bg[64+c] * rsqrtf(bv[64+c] + EPSB);
    x3s[c][j - o3s] = lrelu((acc - bm[64+c]) * sc + bb[64+c]);
  }
  __syncthreads();
  const int np1 = o1e - o1s, np2 = o2e - o2s, np3 = o3e - o3s;
  const int np = np1 + np2 + np3;
  for (int idx = t; idx < np*32; idx += 256) {
    int pi = idx >> 5, s = idx & 31;
    float acc = 0.f;
    int p;
    if (pi < np1) {
      int j = o1s + pi; p = j;
      int col = j - n1s;
      for (int ci = 0; ci < 32; ++ci) acc += lw[s*32 + ci] * x1s[ci][col];
    } else if (pi < np1 + np2) {
      int j = o2s + (pi - np1); p = 937 + j;
      int col = j - n2s;
      for (int ci = 0; ci < 32; ++ci) acc += lw[s*32 + ci] * x2s[ci][col];
    } else {
      int j = o3s + (pi - np1 - np2); p = 1171 + j;
      int col = j - o3s;
      for (int ci = 0; ci < 32; ++ci) acc += lw[s*32 + ci] * x3s[ci][col];
    }
    float sc = bg[96+s] * rsqrtf(bv[96+s] + EPSB);
    xt[p*1024 + b*32 + s] = lrelu((acc - bm[96+s]) * sc + bb[96+s]);
  }
}

// ---------------------------------------------------------------------------
// Pass A v4: u[q4][p(1288)][l][v][b4] = sum_s W[l,p,v,s] x[b,p,s].
// Block = 512 thr = 8 waves sharing one xs tile (8 waves/CU guaranteed;
// LDS 112KB -> 1 block/CU). Wave wv handles l = lg*8+wv over an 8-p chunk.
// Peeled pp0 (vmcnt 5) / pp1 (vmcnt 10), rolled pp=2..7 with uniform
// vmcnt(10): entering pp the per-wave queue is [D(p),S(p-2),D(p+1),S(p-1)]
// = 20 ops; wait(10) drains exactly D(p)+S(p-2), keeping D(p+1) in flight.
// ---------------------------------------------------------------------------
__global__ __launch_bounds__(512) void k_uhat(
    const float* __restrict__ W, const float* __restrict__ xt,
    float* __restrict__ u, float* __restrict__ s0part)
{
  extern __shared__ float lds[];
  float* xs = lds;                       // [8 p][32 b][32 s] swizzled (32KB)
  float* wbuf = lds + 8192;              // [8 waves][2][1280] (80KB)
  const int t = threadIdx.x;
  const int wv = t >> 6, lane = t & 63;
  const int lg = blockIdx.x % 5, chunk = blockIdx.x / 5;
  const int l = lg*8 + wv;
  const int vg = lane >> 3, bg = lane & 7;
  const int p0 = chunk * 8;              // p0 <= 1280
  float* myw = wbuf + wv * 2560;
  const float* Wl = W + (size_t)l * 1287 * 1280;

  // stage x chunk into LDS (swizzled: s4 ^= b>>2); zeros for p >= 1287
  for (int g = t; g < 2048; g += 512) {
    int pl = g >> 8, rem = g & 255;
    int b = rem >> 3, s4 = rem & 7;
    int pg = p0 + pl;
    float4 v = make_float4(0.f, 0.f, 0.f, 0.f);
    if (pg < 1287) v = *(const float4*)(xt + pg*1024 + b*32 + s4*4);
    *(float4*)(xs + pl*1024 + b*32 + ((s4 ^ (b >> 2)) << 2)) = v;
  }
  __syncthreads();
  // prologue DMA (AFTER barrier -- wbuf is wave-private, and this keeps the
  // barrier's vmcnt(0) drain from eating the prologue): D(p0)->b0, D(p0+1)->b1
  #pragma unroll
  for (int i = 0; i < 5; ++i) {
    int g = i*64 + lane, v = g >> 3, s4 = (g & 7) ^ (v & 7);
    gload16(Wl + (size_t)p0*1280 + (v*8 + s4)*4, myw + i*256);
  }
  #pragma unroll
  for (int i = 0; i < 5; ++i) {
    int g = i*64 + lane, v = g >> 3, s4 = (g & 7) ^ (v & 7);
    gload16(Wl + (size_t)(p0+1)*1280 + (v*8 + s4)*4, myw + 1280 + i*256);
  }

  float s0acc[5][4] = {};

  // one pipeline step: compute p from buf(pp&1), prefetch p+2 into same buf,
  // store u(p). Caller did the vmcnt wait.
  auto body = [&](int pp) {
    const int p = p0 + pp;
    const float* wb = myw + (pp & 1)*1280;
    const float* xp = xs + pp*1024;
    float acc[5][4] = {};
    #pragma unroll
    for (int s4 = 0; s4 < 8; ++s4) {
      float4 wv4[5], xv[4];
      #pragma unroll
      for (int i = 0; i < 5; ++i) {
        int v = vg*5 + i;
        wv4[i] = *(const float4*)(wb + v*32 + ((s4 ^ (v & 7)) << 2));
      }
      #pragma unroll
      for (int j = 0; j < 4; ++j) {
        int b = bg*4 + j;
        xv[j] = *(const float4*)(xp + b*32 + ((s4 ^ (b >> 2)) << 2));
      }
      #pragma unroll
      for (int i = 0; i < 5; ++i)
        #pragma unroll
        for (int j = 0; j < 4; ++j)
          acc[i][j] += wv4[i].x*xv[j].x + wv4[i].y*xv[j].y + wv4[i].z*xv[j].z + wv4[i].w*xv[j].w;
    }
    // all ds_reads must land before DMA may overwrite this buffer
    WAITLGKM0;
    __builtin_amdgcn_sched_barrier(0);
    {
      int psrc = p + 2; if (psrc > 1286) psrc = 1286;   // clamped dummy ok
      #pragma unroll
      for (int i = 0; i < 5; ++i) {
        int g = i*64 + lane, v = g >> 3, s4 = (g & 7) ^ (v & 7);
        gload16(Wl + (size_t)psrc*1280 + (v*8 + s4)*4, myw + (pp & 1)*1280 + i*256);
      }
    }
    float* up = u + ((size_t)(bg*1288 + p))*6400 + l*160;
    #pragma unroll
    for (int i = 0; i < 5; ++i) {
      *(float4*)(up + (vg*5 + i)*4) =
          make_float4(acc[i][0], acc[i][1], acc[i][2], acc[i][3]);
      #pragma unroll
      for (int j = 0; j < 4; ++j) s0acc[i][j] += acc[i][j];
    }
  };

  WAITVM(5);   body(0);   // queue was [D0,D1]=10; drains D0
  WAITVM(10);  body(1);   // queue [D1,D2,S0]=15; drains D1
  #pragma unroll 1
  for (int pp = 2; pp < 8; ++pp) {
    WAITVM(10);           // queue [D(p),S(p-2),D(p+1),S(p-1)]=20; drains 10
    body(pp);
  }

  float* sp = s0part + (size_t)chunk*51200 + l*1280;
  #pragma unroll
  for (int i = 0; i < 5; ++i) {
    int v = vg*5 + i;
    *(float4*)(sp + v*32 + bg*4) =
        make_float4(s0acc[i][0], s0acc[i][1], s0acc[i][2], s0acc[i][3]);
  }
}

// ---------------------------------------------------------------------------
// squash0: s0 [lv][b32] -> v0t [q4][l][v][b4], scaled by 1/40 (uniform c).
// ---------------------------------------------------------------------------
__global__ __launch_bounds__(64) void k_squash0(
    const float* __restrict__ s0, float* __restrict__ v0t)
{
  const int b = blockIdx.x / 40, l = blockIdx.x % 40, t = threadIdx.x;
  float s = 0.f;
  if (t < 40) s = s0[(l*40 + t)*32 + b] * (1.f/40.f);
  float sq = s*s;
  #pragma unroll
  for (int d = 1; d < 64; d <<= 1) sq += __shfl_xor(sq, d);
  float scale = sq > 0.f ? sq / ((1.f + sq) * sqrtf(sq)) : 0.f;
  if (t < 40) v0t[((size_t)(b >> 2)*1600 + l*40 + t)*4 + (b & 3)] = s * scale;
}

__global__ __launch_bounds__(64) void k_squash1(
    const float* __restrict__ sred, float* __restrict__ v1t)
{
  const int b = blockIdx.x / 40, l = blockIdx.x % 40, t = threadIdx.x;
  float s = 0.f;
  size_t off = ((size_t)(b >> 2)*1600 + l*40 + t)*4 + (b & 3);
  if (t < 40) s = sred[off];
  float sq = s*s;
  #pragma unroll
  for (int d = 1; d < 64; d <<= 1) sq += __shfl_xor(sq, d);
  float scale = sq > 0.f ? sq / ((1.f + sq) * sqrtf(sq)) : 0.f;
  if (t < 40) v1t[off] = s * scale;
}

__global__ __launch_bounds__(64) void k_final(
    const float* __restrict__ sred, float* __restrict__ out)
{
  const int b = blockIdx.x / 40, l = blockIdx.x % 40, t = threadIdx.x;
  float s = 0.f;
  if (t < 40) s = sred[((size_t)(b >> 2)*1600 + l*40 + t)*4 + (b & 3)];
  float sq = s*s, ss = s;
  #pragma unroll
  for (int d = 1; d < 64; d <<= 1) { sq += __shfl_xor(sq, d); ss += __shfl_xor(ss, d); }
  float scale = sq > 0.f ? sq / ((1.f + sq) * sqrtf(sq)) : 0.f;
  if (t == 0) out[b*40 + l] = ss * scale;
}

// ---------------------------------------------------------------------------
// k_dot / k_soft / k_sacc: unchanged (validated); u p-stride 1288.
// ---------------------------------------------------------------------------
__global__ __launch_bounds__(256) void k_dot(
    const float* __restrict__ u, const float* __restrict__ vprev,
    float* __restrict__ b1g, int pass)
{
  const int tid = blockIdx.x*256 + threadIdx.x;
  if (tid >= 411840) return;
  const int l = tid % 40;
  const int y = tid / 40;
  const int p = y % 1287, q4 = y / 1287;
  const float4* up = (const float4*)(u + (size_t)(q4*1288 + p)*6400 + l*160);
  const float4* vp = (const float4*)(vprev + ((size_t)q4*1600 + l*40)*4);
  float4 d = make_float4(0.f, 0.f, 0.f, 0.f);
  #pragma unroll 8
  for (int v = 0; v < 40; ++v) {
    float4 uu = up[v], vv = vp[v];
    d.x += uu.x*vv.x; d.y += uu.y*vv.y; d.z += uu.z*vv.z; d.w += uu.w*vv.w;
  }
  float4* bp = (float4*)(b1g + (size_t)tid*4);
  if (pass == 2) {
    float4 o = *bp;
    d.x += o.x; d.y += o.y; d.z += o.z; d.w += o.w;
  }
  *bp = d;
}

__global__ __launch_bounds__(256) void k_soft(
    const float* __restrict__ b1g, float* __restrict__ c_g)
{
  const int tid = blockIdx.x*256 + threadIdx.x;
  if (tid >= 41184) return;
  const int b4 = tid & 3, qp = tid >> 2;
  const float* base = b1g + (size_t)qp*160 + b4;
  float e[40];
  float m = -1e30f;
  #pragma unroll
  for (int li = 0; li < 40; ++li) { e[li] = base[li*4]; m = fmaxf(m, e[li]); }
  float Z = 0.f;
  #pragma unroll
  for (int li = 0; li < 40; ++li) { e[li] = expf(e[li] - m); Z += e[li]; }
  float r = 1.f / Z;
  float* cb = c_g + (size_t)qp*160 + b4;
  #pragma unroll
  for (int li = 0; li < 40; ++li) cb[li*4] = e[li] * r;
}

#define PC 10
__global__ __launch_bounds__(320) void k_sacc(
    const float* __restrict__ u, const float* __restrict__ c_g,
    float* __restrict__ spart)
{
  const int q4 = blockIdx.x & 7, chunk = blockIdx.x >> 3;
  const int t = threadIdx.x;
  float4 sreg[5];
  int l4[5];
  #pragma unroll
  for (int k = 0; k < 5; ++k) {
    sreg[k] = make_float4(0.f, 0.f, 0.f, 0.f);
    l4[k] = (k*320 + t) / 40;
  }
  const int p0 = chunk * PC;
  #pragma unroll 2
  for (int pp = 0; pp < PC; ++pp) {
    int p = p0 + pp;
    if (p >= 1287) break;
    const float4* up = (const float4*)(u + (size_t)(q4*1288 + p)*6400);
    const float4* cp = (const float4*)(c_g + (size_t)(q4*1287 + p)*160);
    #pragma unroll
    for (int k = 0; k < 5; ++k) {
      float4 uu = up[k*320 + t];
      float4 cc = cp[l4[k]];
      sreg[k].x += uu.x*cc.x; sreg[k].y += uu.y*cc.y;
      sreg[k].z += uu.z*cc.z; sreg[k].w += uu.w*cc.w;
    }
  }
  float4* sp = (float4*)(spart + ((size_t)chunk*8 + q4)*6400);
  #pragma unroll
  for (int k = 0; k < 5; ++k) sp[k*320 + t] = sreg[k];
}

// sout[w] = sum_{c<n} src[c][w], w < 51200
__global__ __launch_bounds__(256) void k_reduceN(
    const float* __restrict__ src, float* __restrict__ sout, int n)
{
  const int w = blockIdx.x*256 + threadIdx.x;
  float s = 0.f;
  #pragma unroll 4
  for (int c = 0; c < n; ++c) s += src[(size_t)c*51200 + w];
  sout[w] = s;
}

// ---------------------------------------------------------------------------
extern "C" void kernel_launch(void* const* d_in, const int* in_sizes, int n_in,
                              void* d_out, int out_size, void* d_ws, size_t ws_size,
                              hipStream_t stream)
{
  const float* data = (const float*)d_in[0];
  const float* w1   = (const float*)d_in[1];
  const float* w2   = (const float*)d_in[2];
  const float* w3   = (const float*)d_in[3];
  const float* lw   = (const float*)d_in[4];
  const float* bg   = (const float*)d_in[5];
  const float* bb   = (const float*)d_in[6];
  const float* bm   = (const float*)d_in[7];
  const float* bv   = (const float*)d_in[8];
  const float* W    = (const float*)d_in[9];
  float* out = (float*)d_out;

  float* u      = (float*)d_ws;            // 8*1288*6400 = 65,945,600
  float* s0     = u + 65945600;            // 51,200
  float* v0t    = s0 + 51200;              // 51,200
  float* v1t    = v0t + 51200;             // 51,200
  float* s1     = v1t + 51200;             // 51,200
  float* xt     = s1 + 51200;              // 1,317,888
  float* big    = xt + 1317888;            // shared region
  float* s0part = big;                     // [161][51200] (dead after reduce)
  float* b1g    = big;                     // 1,647,360
  float* c_g    = b1g + 1647360;           // 1,647,360
  float* spart  = c_g + 1647360;           // 6,604,800
  // total ~310 MB

  const int KU_LDS = (8192 + 8*2*1280) * 4;  // 114,688 B
  hipFuncSetAttribute((const void*)k_uhat,
                      hipFuncAttributeMaxDynamicSharedMemorySize, KU_LDS);

  k_front<<<256, 256, 0, stream>>>(data, w1, w2, w3, lw, bg, bb, bm, bv, xt);
  k_uhat<<<805, 512, KU_LDS, stream>>>(W, xt, u, s0part);
  k_reduceN<<<200, 256, 0, stream>>>(s0part, s0, 161);
  k_squash0<<<1280, 64, 0, stream>>>(s0, v0t);

  k_dot<<<1609, 256, 0, stream>>>(u, v0t, b1g, 1);
  k_soft<<<161, 256, 0, stream>>>(b1g, c_g);
  k_sacc<<<1032, 320, 0, stream>>>(u, c_g, spart);
  k_reduceN<<<200, 256, 0, stream>>>(spart, s1, 129);
  k_squash1<<<1280, 64, 0, stream>>>(s1, v1t);

  k_dot<<<1609, 256, 0, stream>>>(u, v1t, b1g, 2);
  k_soft<<<161, 256, 0, stream>>>(b1g, c_g);
  k_sacc<<<1032, 320, 0, stream>>>(u, c_g, spart);
  k_reduceN<<<200, 256, 0, stream>>>(spart, s0, 129);
  k_final<<<1280, 64, 0, stream>>>(s0, out);
}

// Round 7
// 552.145 us; speedup vs baseline: 1.2677x; 1.2677x over previous
//
#include <hip/hip_runtime.h>

#define EPSB 1e-5f
#define NEG 0.2f

__device__ __forceinline__ float lrelu(float y) { return y >= 0.f ? y : NEG * y; }

// async global->LDS 16B/lane (wave-uniform LDS dest, per-lane global src)
typedef const __attribute__((address_space(1))) unsigned int gas1_u32;
typedef __attribute__((address_space(3))) unsigned int as3_u32;
__device__ __forceinline__ void gload16(const float* g, float* l) {
  __builtin_amdgcn_global_load_lds((gas1_u32*)g, (as3_u32*)l, 16, 0, 0);
}
#define WAITVM(N) asm volatile("s_waitcnt vmcnt(" #N ")" ::: "memory")

// ---------------------------------------------------------------------------
// Fused conv frontend (unchanged, validated): output xt[p][b][s].
// ---------------------------------------------------------------------------
__global__ __launch_bounds__(256) void k_front(
    const float* __restrict__ data, const float* __restrict__ w1,
    const float* __restrict__ w2, const float* __restrict__ w3,
    const float* __restrict__ lw, const float* __restrict__ bg,
    const float* __restrict__ bb, const float* __restrict__ bm,
    const float* __restrict__ bv, float* __restrict__ xt)
{
  __shared__ float x1s[32][132];
  __shared__ float x2s[32][40];
  __shared__ float x3s[32][20];
  const int b = blockIdx.x >> 3, q = blockIdx.x & 7, t = threadIdx.x;
  const int o1s = (937*q)/8, o1e = (937*(q+1))/8;
  const int o2s = (234*q)/8, o2e = (234*(q+1))/8;
  const int o3s = (116*q)/8, o3e = (116*(q+1))/8;
  int n2s = min(o2s, 2*o3s);
  int n2e = max(o2e, 2*(o3e-1)+4); if (n2e > 234) n2e = 234;
  int n1s = min(o1s, 4*n2s);
  int n1e = max(o1e, 4*(n2e-1)+5); if (n1e > 937) n1e = 937;
  const int w1w = n1e - n1s, w2w = n2e - n2s, w3w = o3e - o3s;

  for (int idx = t; idx < 32*w1w; idx += 256) {
    int c = idx / w1w, j = n1s + idx % w1w;
    float acc = 0.f;
    int base = 5*j - 2;
    #pragma unroll
    for (int k = 0; k < 5; ++k) {
      int pos = base + k;
      float d = (pos >= 0 && pos < 4681) ? data[b*4681 + pos] : 0.f;
      acc += w1[c*5 + k] * d;
    }
    float sc = bg[c] * rsqrtf(bv[c] + EPSB);
    x1s[c][j - n1s] = lrelu((acc - bm[c]) * sc + bb[c]);
  }
  __syncthreads();
  for (int idx = t; idx < 32*w2w; idx += 256) {
    int c = idx / w2w, j = n2s + idx % w2w;
    float acc = 0.f;
    int col = 4*j - n1s;
    for (int ci = 0; ci < 32; ++ci) {
      #pragma unroll
      for (int k = 0; k < 5; ++k) acc += w2[(c*32 + ci)*5 + k] * x1s[ci][col + k];
    }
    float sc = bg[32+c] * rsqrtf(bv[32+c] + EPSB);
    x2s[c][j - n2s] = lrelu((acc - bm[32+c]) * sc + bb[32+c]);
  }
  __syncthreads();
  for (int idx = t; idx < 32*w3w; idx += 256) {
    int c = idx / w3w, j = o3s + idx % w3w;
    float acc = 0.f;
    int col = 2*j - n2s;
    for (int ci = 0; ci < 32; ++ci) {
      #pragma unroll
      for (int k = 0; k < 4; ++k) acc += w3[(c*32 + ci)*4 + k] * x2s[ci][col + k];
    }
    float sc = bg[64+c] * rsqrtf(bv[64+c] + EPSB);
    x3s[c][j - o3s] = lrelu((acc - bm[64+c]) * sc + bb[64+c]);
  }
  __syncthreads();
  const int np1 = o1e - o1s, np2 = o2e - o2s, np3 = o3e - o3s;
  const int np = np1 + np2 + np3;
  for (int idx = t; idx < np*32; idx += 256) {
    int pi = idx >> 5, s = idx & 31;
    float acc = 0.f;
    int p;
    if (pi < np1) {
      int j = o1s + pi; p = j;
      int col = j - n1s;
      for (int ci = 0; ci < 32; ++ci) acc += lw[s*32 + ci] * x1s[ci][col];
    } else if (pi < np1 + np2) {
      int j = o2s + (pi - np1); p = 937 + j;
      int col = j - n2s;
      for (int ci = 0; ci < 32; ++ci) acc += lw[s*32 + ci] * x2s[ci][col];
    } else {
      int j = o3s + (pi - np1 - np2); p = 1171 + j;
      int col = j - o3s;
      for (int ci = 0; ci < 32; ++ci) acc += lw[s*32 + ci] * x3s[ci][col];
    }
    float sc = bg[96+s] * rsqrtf(bv[96+s] + EPSB);
    xt[p*1024 + b*32 + s] = lrelu((acc - bm[96+s]) * sc + bb[96+s]);
  }
}

// ---------------------------------------------------------------------------
// Pass A: EXACT R4 version (best measured: 193 us). u stride 1287.
// ---------------------------------------------------------------------------
__global__ __launch_bounds__(256) void k_uhat(
    const float* __restrict__ W, const float* __restrict__ xt,
    float* __restrict__ u, float* __restrict__ s0part)
{
  extern __shared__ float lds[];
  float* xs = lds;                       // [8 p][32 b][32 s] swizzled
  float* wbuf = lds + 8192;              // [4 waves][2][1280]
  const int t = threadIdx.x;
  const int wi = blockIdx.x*4 + (t >> 6);
  const int lane = t & 63;
  const int l = wi % 40, chunk = wi / 40;
  const int vg = lane >> 3, bg = lane & 7;
  const int p0 = chunk * 8;
  float* myw = wbuf + (t >> 6) * 2560;
  const float* Wl = W + (size_t)l * 1287 * 1280;

  for (int g = t; g < 2048; g += 256) {
    int pl = g >> 8, rem = g & 255;
    int b = rem >> 3, s4 = rem & 7;
    int pg = p0 + pl;
    float4 v = make_float4(0.f, 0.f, 0.f, 0.f);
    if (pg < 1287) v = *(const float4*)(xt + pg*1024 + b*32 + s4*4);
    *(float4*)(xs + pl*1024 + b*32 + ((s4 ^ (b >> 2)) << 2)) = v;
  }
  {
    #pragma unroll
    for (int i = 0; i < 5; ++i) {
      int g = i*64 + lane, v = g >> 3, s4 = (g & 7) ^ (v & 7);
      gload16(Wl + (size_t)p0*1280 + (v*8 + s4)*4, myw + i*256);
    }
    if (p0 + 1 < 1287) {
      #pragma unroll
      for (int i = 0; i < 5; ++i) {
        int g = i*64 + lane, v = g >> 3, s4 = (g & 7) ^ (v & 7);
        gload16(Wl + (size_t)(p0+1)*1280 + (v*8 + s4)*4, myw + 1280 + i*256);
      }
    }
  }
  __syncthreads();

  float s0acc[5][4] = {};
  int cur = 0;
  for (int pp = 0; pp < 8; ++pp) {
    int p = p0 + pp;
    if (p >= 1287) break;
    asm volatile("s_waitcnt lgkmcnt(0)" ::: "memory");
    WAITVM(5);
    const float* wb = myw + cur*1280;
    const float* xp = xs + pp*1024;
    float acc[5][4] = {};
    #pragma unroll
    for (int s4 = 0; s4 < 8; ++s4) {
      float4 wv[5], xv[4];
      #pragma unroll
      for (int i = 0; i < 5; ++i) {
        int v = vg*5 + i;
        wv[i] = *(const float4*)(wb + v*32 + ((s4 ^ (v & 7)) << 2));
      }
      #pragma unroll
      for (int j = 0; j < 4; ++j) {
        int b = bg*4 + j;
        xv[j] = *(const float4*)(xp + b*32 + ((s4 ^ (b >> 2)) << 2));
      }
      #pragma unroll
      for (int i = 0; i < 5; ++i)
        #pragma unroll
        for (int j = 0; j < 4; ++j)
          acc[i][j] += wv[i].x*xv[j].x + wv[i].y*xv[j].y + wv[i].z*xv[j].z + wv[i].w*xv[j].w;
    }
    if (pp < 6 && p + 2 < 1287) {
      asm volatile("s_waitcnt lgkmcnt(0)" ::: "memory");
      #pragma unroll
      for (int i = 0; i < 5; ++i) {
        int g = i*64 + lane, v = g >> 3, s4 = (g & 7) ^ (v & 7);
        gload16(Wl + (size_t)(p+2)*1280 + (v*8 + s4)*4, myw + cur*1280 + i*256);
      }
    }
    float* up = u + ((size_t)(bg*1287 + p))*6400 + l*160;
    #pragma unroll
    for (int i = 0; i < 5; ++i) {
      int v = vg*5 + i;
      *(float4*)(up + v*4) = make_float4(acc[i][0], acc[i][1], acc[i][2], acc[i][3]);
      #pragma unroll
      for (int j = 0; j < 4; ++j) s0acc[i][j] += acc[i][j];
    }
    cur ^= 1;
  }
  float* sp = s0part + (size_t)chunk*51200 + l*1280;
  #pragma unroll
  for (int i = 0; i < 5; ++i) {
    int v = vg*5 + i;
    *(float4*)(sp + v*32 + bg*4) =
        make_float4(s0acc[i][0], s0acc[i][1], s0acc[i][2], s0acc[i][3]);
  }
}

// ---------------------------------------------------------------------------
// squash kernels (unchanged, validated)
// ---------------------------------------------------------------------------
__global__ __launch_bounds__(64) void k_squash0(
    const float* __restrict__ s0, float* __restrict__ v0t)
{
  const int b = blockIdx.x / 40, l = blockIdx.x % 40, t = threadIdx.x;
  float s = 0.f;
  if (t < 40) s = s0[(l*40 + t)*32 + b] * (1.f/40.f);
  float sq = s*s;
  #pragma unroll
  for (int d = 1; d < 64; d <<= 1) sq += __shfl_xor(sq, d);
  float scale = sq > 0.f ? sq / ((1.f + sq) * sqrtf(sq)) : 0.f;
  if (t < 40) v0t[((size_t)(b >> 2)*1600 + l*40 + t)*4 + (b & 3)] = s * scale;
}

__global__ __launch_bounds__(64) void k_squash1(
    const float* __restrict__ sred, float* __restrict__ v1t)
{
  const int b = blockIdx.x / 40, l = blockIdx.x % 40, t = threadIdx.x;
  float s = 0.f;
  size_t off = ((size_t)(b >> 2)*1600 + l*40 + t)*4 + (b & 3);
  if (t < 40) s = sred[off];
  float sq = s*s;
  #pragma unroll
  for (int d = 1; d < 64; d <<= 1) sq += __shfl_xor(sq, d);
  float scale = sq > 0.f ? sq / ((1.f + sq) * sqrtf(sq)) : 0.f;
  if (t < 40) v1t[off] = s * scale;
}

__global__ __launch_bounds__(64) void k_final(
    const float* __restrict__ sred, float* __restrict__ out)
{
  const int b = blockIdx.x / 40, l = blockIdx.x % 40, t = threadIdx.x;
  float s = 0.f;
  if (t < 40) s = sred[((size_t)(b >> 2)*1600 + l*40 + t)*4 + (b & 3)];
  float sq = s*s, ss = s;
  #pragma unroll
  for (int d = 1; d < 64; d <<= 1) { sq += __shfl_xor(sq, d); ss += __shfl_xor(ss, d); }
  float scale = sq > 0.f ? sq / ((1.f + sq) * sqrtf(sq)) : 0.f;
  if (t == 0) out[b*40 + l] = ss * scale;
}

// ---------------------------------------------------------------------------
// k_route2: FUSED dot + softmax + s-accumulate (softmax over l is per-(b,p)
// local, so routing needs no global sync). Block = (q4, chunk of 12 p).
// Phase A (t<480, t=(pl,l)): dot4[l] = sum_v u4*vp4 (contiguous 640B run);
//   pass2 adds stored b1g; pass1 stores b1g. -> dot_lds.
// Phase B (t<48, t=(pl,b4)): softmax over 40 l -> c_lds.
// Phase C (t<400): s4[k] += u4 (coalesced re-read, L2/L3-hot) * c broadcast;
//   writes spart[chunk*8+q4][6400]. Two barriers per block total; no atomics.
// ---------------------------------------------------------------------------
#define RPC 12
#define NCHUNK 108              // ceil(1287/12)
__global__ __launch_bounds__(512) void k_route2(
    const float* __restrict__ u, const float* __restrict__ vprev,
    float* __restrict__ b1g, float* __restrict__ spart, int pass)
{
  __shared__ float dot_lds[RPC*160];
  __shared__ float c_lds[RPC*160];
  const int q4 = blockIdx.x & 7, chunk = blockIdx.x >> 3;
  const int t = threadIdx.x;
  const int p0 = chunk * RPC;

  // Phase A: dots
  if (t < 480) {
    const int pl = t / 40, l = t % 40;
    const int p = p0 + pl;
    if (p < 1287) {
      const size_t qp = (size_t)q4*1287 + p;
      const float4* up = (const float4*)u + qp*1600 + l*40;
      const float4* vp = (const float4*)vprev + (size_t)q4*1600 + l*40;
      float4 d = make_float4(0.f, 0.f, 0.f, 0.f);
      #pragma unroll 8
      for (int v = 0; v < 40; ++v) {
        float4 uu = up[v], vv = vp[v];
        d.x += uu.x*vv.x; d.y += uu.y*vv.y; d.z += uu.z*vv.z; d.w += uu.w*vv.w;
      }
      float4* bp = (float4*)b1g + qp*40 + l;
      if (pass == 2) {
        float4 o = *bp;
        d.x += o.x; d.y += o.y; d.z += o.z; d.w += o.w;
      } else {
        *bp = d;
      }
      *(float4*)(dot_lds + pl*160 + l*4) = d;
    }
  }
  __syncthreads();
  // Phase B: softmax over l per (pl, b4)
  if (t < 4*RPC) {
    const int pl = t >> 2, b4 = t & 3;
    if (p0 + pl < 1287) {
      const float* dl = dot_lds + pl*160 + b4;
      float m = -1e30f;
      for (int li = 0; li < 40; ++li) m = fmaxf(m, dl[li*4]);
      float Z = 0.f;
      float* cl = c_lds + pl*160 + b4;
      for (int li = 0; li < 40; ++li) {
        float e = expf(dl[li*4] - m);
        cl[li*4] = e; Z += e;
      }
      float r = 1.f / Z;
      for (int li = 0; li < 40; ++li) cl[li*4] *= r;
    }
  }
  __syncthreads();
  // Phase C: s accumulate (coalesced), 400 threads x 4 float4
  if (t < 400) {
    float4 s4[4];
    #pragma unroll
    for (int k = 0; k < 4; ++k) s4[k] = make_float4(0.f, 0.f, 0.f, 0.f);
    const int npc = (1287 - p0 < RPC) ? (1287 - p0) : RPC;
    for (int pl = 0; pl < npc; ++pl) {
      const float4* up = (const float4*)u + ((size_t)q4*1287 + p0 + pl)*1600;
      const float* cl = c_lds + pl*160;
      #pragma unroll
      for (int k = 0; k < 4; ++k) {
        int f = k*400 + t;
        float4 uu = up[f];
        float4 cc = *(const float4*)(cl + (f/40)*4);
        s4[k].x += uu.x*cc.x; s4[k].y += uu.y*cc.y;
        s4[k].z += uu.z*cc.z; s4[k].w += uu.w*cc.w;
      }
    }
    float4* sp = (float4*)spart + ((size_t)chunk*8 + q4)*1600;
    #pragma unroll
    for (int k = 0; k < 4; ++k) sp[k*400 + t] = s4[k];
  }
}

// sout[w] = sum_{c<n} src[c][w], w < 51200
__global__ __launch_bounds__(256) void k_reduceN(
    const float* __restrict__ src, float* __restrict__ sout, int n)
{
  const int w = blockIdx.x*256 + threadIdx.x;
  float s = 0.f;
  #pragma unroll 4
  for (int c = 0; c < n; ++c) s += src[(size_t)c*51200 + w];
  sout[w] = s;
}

// ---------------------------------------------------------------------------
extern "C" void kernel_launch(void* const* d_in, const int* in_sizes, int n_in,
                              void* d_out, int out_size, void* d_ws, size_t ws_size,
                              hipStream_t stream)
{
  const float* data = (const float*)d_in[0];
  const float* w1   = (const float*)d_in[1];
  const float* w2   = (const float*)d_in[2];
  const float* w3   = (const float*)d_in[3];
  const float* lw   = (const float*)d_in[4];
  const float* bg   = (const float*)d_in[5];
  const float* bb   = (const float*)d_in[6];
  const float* bm   = (const float*)d_in[7];
  const float* bv   = (const float*)d_in[8];
  const float* W    = (const float*)d_in[9];
  float* out = (float*)d_out;

  float* u      = (float*)d_ws;            // 8*1287*6400 = 65,894,400
  float* s0     = u + 65894400;            // 51,200
  float* v0t    = s0 + 51200;              // 51,200
  float* v1t    = v0t + 51200;             // 51,200
  float* s1     = v1t + 51200;             // 51,200
  float* xt     = s1 + 51200;              // 1,317,888
  float* big    = xt + 1317888;
  float* s0part = big;                     // [161][51200] (dead after reduce)
  float* b1g    = big;                     // 1,647,360 (survives pass1->pass2)
  float* spart  = b1g + 1647360;           // [108][51200] = 5,529,600
  // total ~303 MB

  const int KU_LDS = (8192 + 4*2*1280) * 4;  // 73,728 B
  hipFuncSetAttribute((const void*)k_uhat,
                      hipFuncAttributeMaxDynamicSharedMemorySize, KU_LDS);

  k_front<<<256, 256, 0, stream>>>(data, w1, w2, w3, lw, bg, bb, bm, bv, xt);
  k_uhat<<<1610, 256, KU_LDS, stream>>>(W, xt, u, s0part);
  k_reduceN<<<200, 256, 0, stream>>>(s0part, s0, 161);
  k_squash0<<<1280, 64, 0, stream>>>(s0, v0t);

  k_route2<<<NCHUNK*8, 512, 0, stream>>>(u, v0t, b1g, spart, 1);
  k_reduceN<<<200, 256, 0, stream>>>(spart, s1, NCHUNK);
  k_squash1<<<1280, 64, 0, stream>>>(s1, v1t);

  k_route2<<<NCHUNK*8, 512, 0, stream>>>(u, v1t, b1g, spart, 2);
  k_reduceN<<<200, 256, 0, stream>>>(spart, s0, NCHUNK);
  k_final<<<1280, 64, 0, stream>>>(s0, out);
}

// Round 8
// 449.663 us; speedup vs baseline: 1.5566x; 1.2279x over previous
//
#include <hip/hip_runtime.h>

#define EPSB 1e-5f
#define NEG 0.2f

__device__ __forceinline__ float lrelu(float y) { return y >= 0.f ? y : NEG * y; }

// async global->LDS 16B/lane (wave-uniform LDS dest, per-lane global src)
typedef const __attribute__((address_space(1))) unsigned int gas1_u32;
typedef __attribute__((address_space(3))) unsigned int as3_u32;
__device__ __forceinline__ void gload16(const float* g, float* l) {
  __builtin_amdgcn_global_load_lds((gas1_u32*)g, (as3_u32*)l, 16, 0, 0);
}
#define WAITVM(N) asm volatile("s_waitcnt vmcnt(" #N ")" ::: "memory")

// ---------------------------------------------------------------------------
// Fused conv frontend (unchanged, validated): output xt[p][b][s].
// ---------------------------------------------------------------------------
__global__ __launch_bounds__(256) void k_front(
    const float* __restrict__ data, const float* __restrict__ w1,
    const float* __restrict__ w2, const float* __restrict__ w3,
    const float* __restrict__ lw, const float* __restrict__ bg,
    const float* __restrict__ bb, const float* __restrict__ bm,
    const float* __restrict__ bv, float* __restrict__ xt)
{
  __shared__ float x1s[32][132];
  __shared__ float x2s[32][40];
  __shared__ float x3s[32][20];
  const int b = blockIdx.x >> 3, q = blockIdx.x & 7, t = threadIdx.x;
  const int o1s = (937*q)/8, o1e = (937*(q+1))/8;
  const int o2s = (234*q)/8, o2e = (234*(q+1))/8;
  const int o3s = (116*q)/8, o3e = (116*(q+1))/8;
  int n2s = min(o2s, 2*o3s);
  int n2e = max(o2e, 2*(o3e-1)+4); if (n2e > 234) n2e = 234;
  int n1s = min(o1s, 4*n2s);
  int n1e = max(o1e, 4*(n2e-1)+5); if (n1e > 937) n1e = 937;
  const int w1w = n1e - n1s, w2w = n2e - n2s, w3w = o3e - o3s;

  for (int idx = t; idx < 32*w1w; idx += 256) {
    int c = idx / w1w, j = n1s + idx % w1w;
    float acc = 0.f;
    int base = 5*j - 2;
    #pragma unroll
    for (int k = 0; k < 5; ++k) {
      int pos = base + k;
      float d = (pos >= 0 && pos < 4681) ? data[b*4681 + pos] : 0.f;
      acc += w1[c*5 + k] * d;
    }
    float sc = bg[c] * rsqrtf(bv[c] + EPSB);
    x1s[c][j - n1s] = lrelu((acc - bm[c]) * sc + bb[c]);
  }
  __syncthreads();
  for (int idx = t; idx < 32*w2w; idx += 256) {
    int c = idx / w2w, j = n2s + idx % w2w;
    float acc = 0.f;
    int col = 4*j - n1s;
    for (int ci = 0; ci < 32; ++ci) {
      #pragma unroll
      for (int k = 0; k < 5; ++k) acc += w2[(c*32 + ci)*5 + k] * x1s[ci][col + k];
    }
    float sc = bg[32+c] * rsqrtf(bv[32+c] + EPSB);
    x2s[c][j - n2s] = lrelu((acc - bm[32+c]) * sc + bb[32+c]);
  }
  __syncthreads();
  for (int idx = t; idx < 32*w3w; idx += 256) {
    int c = idx / w3w, j = o3s + idx % w3w;
    float acc = 0.f;
    int col = 2*j - n2s;
    for (int ci = 0; ci < 32; ++ci) {
      #pragma unroll
      for (int k = 0; k < 4; ++k) acc += w3[(c*32 + ci)*4 + k] * x2s[ci][col + k];
    }
    float sc = bg[64+c] * rsqrtf(bv[64+c] + EPSB);
    x3s[c][j - o3s] = lrelu((acc - bm[64+c]) * sc + bb[64+c]);
  }
  __syncthreads();
  const int np1 = o1e - o1s, np2 = o2e - o2s, np3 = o3e - o3s;
  const int np = np1 + np2 + np3;
  for (int idx = t; idx < np*32; idx += 256) {
    int pi = idx >> 5, s = idx & 31;
    float acc = 0.f;
    int p;
    if (pi < np1) {
      int j = o1s + pi; p = j;
      int col = j - n1s;
      for (int ci = 0; ci < 32; ++ci) acc += lw[s*32 + ci] * x1s[ci][col];
    } else if (pi < np1 + np2) {
      int j = o2s + (pi - np1); p = 937 + j;
      int col = j - n2s;
      for (int ci = 0; ci < 32; ++ci) acc += lw[s*32 + ci] * x2s[ci][col];
    } else {
      int j = o3s + (pi - np1 - np2); p = 1171 + j;
      int col = j - o3s;
      for (int ci = 0; ci < 32; ++ci) acc += lw[s*32 + ci] * x3s[ci][col];
    }
    float sc = bg[96+s] * rsqrtf(bv[96+s] + EPSB);
    xt[p*1024 + b*32 + s] = lrelu((acc - bm[96+s]) * sc + bb[96+s]);
  }
}

// ---------------------------------------------------------------------------
// Pass A: EXACT R4 version (best measured: 193 us). u stride 1287.
// ---------------------------------------------------------------------------
__global__ __launch_bounds__(256) void k_uhat(
    const float* __restrict__ W, const float* __restrict__ xt,
    float* __restrict__ u, float* __restrict__ s0part)
{
  extern __shared__ float lds[];
  float* xs = lds;                       // [8 p][32 b][32 s] swizzled
  float* wbuf = lds + 8192;              // [4 waves][2][1280]
  const int t = threadIdx.x;
  const int wi = blockIdx.x*4 + (t >> 6);
  const int lane = t & 63;
  const int l = wi % 40, chunk = wi / 40;
  const int vg = lane >> 3, bg = lane & 7;
  const int p0 = chunk * 8;
  float* myw = wbuf + (t >> 6) * 2560;
  const float* Wl = W + (size_t)l * 1287 * 1280;

  for (int g = t; g < 2048; g += 256) {
    int pl = g >> 8, rem = g & 255;
    int b = rem >> 3, s4 = rem & 7;
    int pg = p0 + pl;
    float4 v = make_float4(0.f, 0.f, 0.f, 0.f);
    if (pg < 1287) v = *(const float4*)(xt + pg*1024 + b*32 + s4*4);
    *(float4*)(xs + pl*1024 + b*32 + ((s4 ^ (b >> 2)) << 2)) = v;
  }
  {
    #pragma unroll
    for (int i = 0; i < 5; ++i) {
      int g = i*64 + lane, v = g >> 3, s4 = (g & 7) ^ (v & 7);
      gload16(Wl + (size_t)p0*1280 + (v*8 + s4)*4, myw + i*256);
    }
    if (p0 + 1 < 1287) {
      #pragma unroll
      for (int i = 0; i < 5; ++i) {
        int g = i*64 + lane, v = g >> 3, s4 = (g & 7) ^ (v & 7);
        gload16(Wl + (size_t)(p0+1)*1280 + (v*8 + s4)*4, myw + 1280 + i*256);
      }
    }
  }
  __syncthreads();

  float s0acc[5][4] = {};
  int cur = 0;
  for (int pp = 0; pp < 8; ++pp) {
    int p = p0 + pp;
    if (p >= 1287) break;
    asm volatile("s_waitcnt lgkmcnt(0)" ::: "memory");
    WAITVM(5);
    const float* wb = myw + cur*1280;
    const float* xp = xs + pp*1024;
    float acc[5][4] = {};
    #pragma unroll
    for (int s4 = 0; s4 < 8; ++s4) {
      float4 wv[5], xv[4];
      #pragma unroll
      for (int i = 0; i < 5; ++i) {
        int v = vg*5 + i;
        wv[i] = *(const float4*)(wb + v*32 + ((s4 ^ (v & 7)) << 2));
      }
      #pragma unroll
      for (int j = 0; j < 4; ++j) {
        int b = bg*4 + j;
        xv[j] = *(const float4*)(xp + b*32 + ((s4 ^ (b >> 2)) << 2));
      }
      #pragma unroll
      for (int i = 0; i < 5; ++i)
        #pragma unroll
        for (int j = 0; j < 4; ++j)
          acc[i][j] += wv[i].x*xv[j].x + wv[i].y*xv[j].y + wv[i].z*xv[j].z + wv[i].w*xv[j].w;
    }
    if (pp < 6 && p + 2 < 1287) {
      asm volatile("s_waitcnt lgkmcnt(0)" ::: "memory");
      #pragma unroll
      for (int i = 0; i < 5; ++i) {
        int g = i*64 + lane, v = g >> 3, s4 = (g & 7) ^ (v & 7);
        gload16(Wl + (size_t)(p+2)*1280 + (v*8 + s4)*4, myw + cur*1280 + i*256);
      }
    }
    float* up = u + ((size_t)(bg*1287 + p))*6400 + l*160;
    #pragma unroll
    for (int i = 0; i < 5; ++i) {
      int v = vg*5 + i;
      *(float4*)(up + v*4) = make_float4(acc[i][0], acc[i][1], acc[i][2], acc[i][3]);
      #pragma unroll
      for (int j = 0; j < 4; ++j) s0acc[i][j] += acc[i][j];
    }
    cur ^= 1;
  }
  float* sp = s0part + (size_t)chunk*51200 + l*1280;
  #pragma unroll
  for (int i = 0; i < 5; ++i) {
    int v = vg*5 + i;
    *(float4*)(sp + v*32 + bg*4) =
        make_float4(s0acc[i][0], s0acc[i][1], s0acc[i][2], s0acc[i][3]);
  }
}

// ---------------------------------------------------------------------------
// squash kernels (unchanged, validated)
// ---------------------------------------------------------------------------
__global__ __launch_bounds__(64) void k_squash0(
    const float* __restrict__ s0, float* __restrict__ v0t)
{
  const int b = blockIdx.x / 40, l = blockIdx.x % 40, t = threadIdx.x;
  float s = 0.f;
  if (t < 40) s = s0[(l*40 + t)*32 + b] * (1.f/40.f);
  float sq = s*s;
  #pragma unroll
  for (int d = 1; d < 64; d <<= 1) sq += __shfl_xor(sq, d);
  float scale = sq > 0.f ? sq / ((1.f + sq) * sqrtf(sq)) : 0.f;
  if (t < 40) v0t[((size_t)(b >> 2)*1600 + l*40 + t)*4 + (b & 3)] = s * scale;
}

__global__ __launch_bounds__(64) void k_squash1(
    const float* __restrict__ sred, float* __restrict__ v1t)
{
  const int b = blockIdx.x / 40, l = blockIdx.x % 40, t = threadIdx.x;
  float s = 0.f;
  size_t off = ((size_t)(b >> 2)*1600 + l*40 + t)*4 + (b & 3);
  if (t < 40) s = sred[off];
  float sq = s*s;
  #pragma unroll
  for (int d = 1; d < 64; d <<= 1) sq += __shfl_xor(sq, d);
  float scale = sq > 0.f ? sq / ((1.f + sq) * sqrtf(sq)) : 0.f;
  if (t < 40) v1t[off] = s * scale;
}

__global__ __launch_bounds__(64) void k_final(
    const float* __restrict__ sred, float* __restrict__ out)
{
  const int b = blockIdx.x / 40, l = blockIdx.x % 40, t = threadIdx.x;
  float s = 0.f;
  if (t < 40) s = sred[((size_t)(b >> 2)*1600 + l*40 + t)*4 + (b & 3)];
  float sq = s*s, ss = s;
  #pragma unroll
  for (int d = 1; d < 64; d <<= 1) { sq += __shfl_xor(sq, d); ss += __shfl_xor(ss, d); }
  float scale = sq > 0.f ? sq / ((1.f + sq) * sqrtf(sq)) : 0.f;
  if (t == 0) out[b*40 + l] = ss * scale;
}

// ---------------------------------------------------------------------------
// k_route3: single-read fused routing pass. Block = (q4, chunk of 13 p),
// 400 threads; thread t = (l = t/10, vq = t%10) owns u[l][vq*4+j][b4quad],
// j<4 (one contiguous 64B load per p). Per p:
//   A: uu[j] load + dot partial vs register vv -> dred[t]
//   B: t<160 reduce 10 partials per (l,b4); fused b1g store(p1)/load-add(p2)
//   C: parallel softmax: t<4 max, t<160 exp, t<4 Z
//   D: s4[j] += uu[j] * c[l][b4] * r[b4]   (u NEVER re-read)
// spart row layout identical to validated k_sacc output.
// ---------------------------------------------------------------------------
#define RPC 13
#define NCHUNK 99               // 99*13 = 1287 exactly
__global__ __launch_bounds__(400) void k_route3(
    const float* __restrict__ u, const float* __restrict__ vprev,
    float* __restrict__ b1g, float* __restrict__ spart, int pass)
{
  __shared__ float4 dred[400];
  __shared__ float dot_lds[160];
  __shared__ float c_lds[160];
  __shared__ float mz[4];
  __shared__ float rz[4];
  const int q4 = blockIdx.x & 7, chunk = blockIdx.x >> 3;
  const int t = threadIdx.x;            // t = l*10 + vq
  const int l = t / 10;
  const int p0 = chunk * RPC;
  const float4* u4 = (const float4*)u;
  const float4* vp4 = (const float4*)vprev + (size_t)q4*1600;

  float4 vv[4], s4[4];
  #pragma unroll
  for (int j = 0; j < 4; ++j) {
    vv[j] = vp4[t*4 + j];
    s4[j] = make_float4(0.f, 0.f, 0.f, 0.f);
  }

  for (int pl = 0; pl < RPC; ++pl) {
    const int p = p0 + pl;
    const size_t qp = (size_t)q4*1287 + p;
    const float4* up = u4 + qp*1600;
    float4 uu[4];
    float4 dp = make_float4(0.f, 0.f, 0.f, 0.f);
    #pragma unroll
    for (int j = 0; j < 4; ++j) {
      uu[j] = up[t*4 + j];
      dp.x += uu[j].x*vv[j].x; dp.y += uu[j].y*vv[j].y;
      dp.z += uu[j].z*vv[j].z; dp.w += uu[j].w*vv[j].w;
    }
    dred[t] = dp;
    __syncthreads();
    if (t < 160) {
      const int lr = t >> 2, b4 = t & 3;
      float d = 0.f;
      #pragma unroll
      for (int vq = 0; vq < 10; ++vq)
        d += ((const float*)&dred[lr*10 + vq])[b4];
      if (pass == 2) d += b1g[qp*160 + t];
      else           b1g[qp*160 + t] = d;
      dot_lds[t] = d;
    }
    __syncthreads();
    if (t < 4) {
      float m = -1e30f;
      for (int li = 0; li < 40; ++li) m = fmaxf(m, dot_lds[li*4 + t]);
      mz[t] = m;
    }
    __syncthreads();
    if (t < 160) c_lds[t] = expf(dot_lds[t] - mz[t & 3]);
    __syncthreads();
    if (t < 4) {
      float Z = 0.f;
      for (int li = 0; li < 40; ++li) Z += c_lds[li*4 + t];
      rz[t] = 1.f / Z;
    }
    __syncthreads();
    {
      float4 cc = *(const float4*)(c_lds + l*4);
      cc.x *= rz[0]; cc.y *= rz[1]; cc.z *= rz[2]; cc.w *= rz[3];
      #pragma unroll
      for (int j = 0; j < 4; ++j) {
        s4[j].x += uu[j].x*cc.x; s4[j].y += uu[j].y*cc.y;
        s4[j].z += uu[j].z*cc.z; s4[j].w += uu[j].w*cc.w;
      }
    }
  }
  float4* sp = (float4*)(spart + ((size_t)chunk*8 + q4)*6400);
  #pragma unroll
  for (int j = 0; j < 4; ++j) sp[t*4 + j] = s4[j];
}

// sout[w] = sum_{c<n} src[c][w], w < 51200
__global__ __launch_bounds__(256) void k_reduceN(
    const float* __restrict__ src, float* __restrict__ sout, int n)
{
  const int w = blockIdx.x*256 + threadIdx.x;
  float s = 0.f;
  #pragma unroll 4
  for (int c = 0; c < n; ++c) s += src[(size_t)c*51200 + w];
  sout[w] = s;
}

// ---------------------------------------------------------------------------
extern "C" void kernel_launch(void* const* d_in, const int* in_sizes, int n_in,
                              void* d_out, int out_size, void* d_ws, size_t ws_size,
                              hipStream_t stream)
{
  const float* data = (const float*)d_in[0];
  const float* w1   = (const float*)d_in[1];
  const float* w2   = (const float*)d_in[2];
  const float* w3   = (const float*)d_in[3];
  const float* lw   = (const float*)d_in[4];
  const float* bg   = (const float*)d_in[5];
  const float* bb   = (const float*)d_in[6];
  const float* bm   = (const float*)d_in[7];
  const float* bv   = (const float*)d_in[8];
  const float* W    = (const float*)d_in[9];
  float* out = (float*)d_out;

  float* u      = (float*)d_ws;            // 8*1287*6400 = 65,894,400
  float* s0     = u + 65894400;            // 51,200
  float* v0t    = s0 + 51200;              // 51,200
  float* v1t    = v0t + 51200;             // 51,200
  float* s1     = v1t + 51200;             // 51,200
  float* xt     = s1 + 51200;              // 1,317,888
  float* big    = xt + 1317888;
  float* s0part = big;                     // [161][51200] (dead after reduce)
  float* b1g    = big;                     // 1,647,360 (live pass1 -> pass2)
  float* spart  = b1g + 1647360;           // [99][51200] = 5,068,800
  // total ~303 MB

  const int KU_LDS = (8192 + 4*2*1280) * 4;  // 73,728 B
  hipFuncSetAttribute((const void*)k_uhat,
                      hipFuncAttributeMaxDynamicSharedMemorySize, KU_LDS);

  k_front<<<256, 256, 0, stream>>>(data, w1, w2, w3, lw, bg, bb, bm, bv, xt);
  k_uhat<<<1610, 256, KU_LDS, stream>>>(W, xt, u, s0part);
  k_reduceN<<<200, 256, 0, stream>>>(s0part, s0, 161);
  k_squash0<<<1280, 64, 0, stream>>>(s0, v0t);

  k_route3<<<NCHUNK*8, 400, 0, stream>>>(u, v0t, b1g, spart, 1);
  k_reduceN<<<200, 256, 0, stream>>>(spart, s1, NCHUNK);
  k_squash1<<<1280, 64, 0, stream>>>(s1, v1t);

  k_route3<<<NCHUNK*8, 400, 0, stream>>>(u, v1t, b1g, spart, 2);
  k_reduceN<<<200, 256, 0, stream>>>(spart, s0, NCHUNK);
  k_final<<<1280, 64, 0, stream>>>(s0, out);
}